// Round 1
// baseline (327.057 us; speedup 1.0000x reference)
//
#include <hip/hip_runtime.h>

#define P 256
#define C 28
#define NPIX (P * P)          // 65536
#define MASK_ELEMS (P * P * C) // 1,835,008

// Prep: bks[i][j][ch] = bk[(i-ch) & 255][j][ch]
// Writes coalesced; reads scattered across rows but bk is 7 MB (L2/L3 resident).
__global__ __launch_bounds__(256) void prep_mask_kernel(
    const float* __restrict__ bk, float* __restrict__ bks) {
    int idx = blockIdx.x * 256 + threadIdx.x;
    if (idx >= MASK_ELEMS) return;
    int ch = idx % C;
    int ij = idx / C;          // i*P + j
    int j = ij & (P - 1);
    int i = ij >> 8;
    int src_row = (i - ch) & (P - 1);
    bks[idx] = bk[(src_row * P + j) * C + ch];
}

// Main: one thread per output pixel. x and bks have identical [pix][ch]
// innermost-contiguous layout -> 7 float4 loads each (112 B = 7*16 B aligned).
__global__ __launch_bounds__(256) void codednet_main_kernel(
    const float* __restrict__ x, const float* __restrict__ bks,
    float* __restrict__ out) {
    int pid = blockIdx.x * 256 + threadIdx.x;    // 0 .. 32*65536-1
    int pix = pid & (NPIX - 1);                  // i*P + j (shared across batch)
    const float4* xp = reinterpret_cast<const float4*>(x + (size_t)pid * C);
    const float4* mp = reinterpret_cast<const float4*>(bks + (size_t)pix * C);
    float acc = 0.f;
#pragma unroll
    for (int k = 0; k < 7; ++k) {
        float4 a = xp[k];
        float4 m = mp[k];
        acc += a.x * m.x + a.y * m.y + a.z * m.z + a.w * m.w;
    }
    out[pid] = acc;
}

// Fallback if ws is too small: gather the shifted mask inline (scalar loads,
// bk stays L2/L3-hot).
__global__ __launch_bounds__(256) void codednet_inline_kernel(
    const float* __restrict__ x, const float* __restrict__ bk,
    float* __restrict__ out) {
    int pid = blockIdx.x * 256 + threadIdx.x;
    int pix = pid & (NPIX - 1);
    int j = pix & (P - 1);
    int i = pix >> 8;
    const float* xp = x + (size_t)pid * C;
    float acc = 0.f;
#pragma unroll
    for (int ch = 0; ch < C; ++ch) {
        int src_row = (i - ch) & (P - 1);
        acc += xp[ch] * bk[(src_row * P + j) * C + ch];
    }
    out[pid] = acc;
}

extern "C" void kernel_launch(void* const* d_in, const int* in_sizes, int n_in,
                              void* d_out, int out_size, void* d_ws, size_t ws_size,
                              hipStream_t stream) {
    const float* x  = (const float*)d_in[0];
    const float* bk = (const float*)d_in[1];
    float* out = (float*)d_out;

    const int total = out_size;                  // 32*256*256 = 2,097,152
    const int nblocks = (total + 255) / 256;     // 8192

    if (ws_size >= (size_t)MASK_ELEMS * sizeof(float)) {
        float* bks = (float*)d_ws;
        prep_mask_kernel<<<(MASK_ELEMS + 255) / 256, 256, 0, stream>>>(bk, bks);
        codednet_main_kernel<<<nblocks, 256, 0, stream>>>(x, bks, out);
    } else {
        codednet_inline_kernel<<<nblocks, 256, 0, stream>>>(x, bk, out);
    }
}

// Round 2
// 321.514 us; speedup vs baseline: 1.0172x; 1.0172x over previous
//
#include <hip/hip_runtime.h>

#define P 256
#define C 28
#define NPIX (P * P)            // 65536
#define MASK_ELEMS (NPIX * C)   // 1,835,008
#define Q 7                     // float4s per pixel (28 floats)
#define BLK 448                 // 64 pixels * 7 float4s; 7 waves
#define PIX_PER_BLK 64
#define BLKS_PER_IMG 1024       // NPIX*Q / BLK = 458752/448

// Prep: bks[i][j][ch] = bk[(i-ch) & 255][j][ch]
// Writes coalesced; reads scattered across rows but bk is 7 MB (L2/L3 resident).
__global__ __launch_bounds__(256) void prep_mask_kernel(
    const float* __restrict__ bk, float* __restrict__ bks) {
    int idx = blockIdx.x * 256 + threadIdx.x;
    if (idx >= MASK_ELEMS) return;
    int ch = idx % C;
    int ij = idx / C;          // i*P + j
    int j = ij & (P - 1);
    int i = ij >> 8;
    int src_row = (i - ch) & (P - 1);
    bks[idx] = bk[(src_row * P + j) * C + ch];
}

// Main: one thread per float4 (28 floats/pixel = 7 float4s, never straddles a
// pixel). All global loads lane-consecutive (fully coalesced, 16 lines/instr).
// Partial dot4s staged in LDS; 64 threads reduce 7 partials each (stride 7,
// gcd(7,32)=1 -> conflict-free) and store coalesced.
__global__ __launch_bounds__(BLK) void codednet_f4_kernel(
    const float4* __restrict__ x4, const float4* __restrict__ m4,
    float* __restrict__ out) {
    __shared__ float s[BLK];
    int t = threadIdx.x;
    int f = blockIdx.x * BLK + t;                 // global float4 idx (<2^24)
    int mf = (blockIdx.x & (BLKS_PER_IMG - 1)) * BLK + t;  // mask float4 idx
    float4 a = x4[f];
    float4 m = m4[mf];
    s[t] = a.x * m.x + a.y * m.y + a.z * m.z + a.w * m.w;
    __syncthreads();
    if (t < PIX_PER_BLK) {
        const float* p = s + t * Q;
        float acc = ((p[0] + p[1]) + (p[2] + p[3])) + ((p[4] + p[5]) + p[6]);
        out[blockIdx.x * PIX_PER_BLK + t] = acc;
    }
}

// Fallback if ws is too small: gather the shifted mask inline (scalar loads,
// bk stays L2/L3-hot).
__global__ __launch_bounds__(256) void codednet_inline_kernel(
    const float* __restrict__ x, const float* __restrict__ bk,
    float* __restrict__ out) {
    int pid = blockIdx.x * 256 + threadIdx.x;
    int pix = pid & (NPIX - 1);
    int j = pix & (P - 1);
    int i = pix >> 8;
    const float* xp = x + (size_t)pid * C;
    float acc = 0.f;
#pragma unroll
    for (int ch = 0; ch < C; ++ch) {
        int src_row = (i - ch) & (P - 1);
        acc += xp[ch] * bk[(src_row * P + j) * C + ch];
    }
    out[pid] = acc;
}

extern "C" void kernel_launch(void* const* d_in, const int* in_sizes, int n_in,
                              void* d_out, int out_size, void* d_ws, size_t ws_size,
                              hipStream_t stream) {
    const float* x  = (const float*)d_in[0];
    const float* bk = (const float*)d_in[1];
    float* out = (float*)d_out;

    const int total = out_size;                  // 32*256*256 = 2,097,152

    if (ws_size >= (size_t)MASK_ELEMS * sizeof(float)) {
        float* bks = (float*)d_ws;
        prep_mask_kernel<<<(MASK_ELEMS + 255) / 256, 256, 0, stream>>>(bk, bks);
        const int nblocks = total / PIX_PER_BLK;  // 32768
        codednet_f4_kernel<<<nblocks, BLK, 0, stream>>>(
            (const float4*)x, (const float4*)bks, out);
    } else {
        codednet_inline_kernel<<<(total + 255) / 256, 256, 0, stream>>>(x, bk, out);
    }
}